// Round 1
// baseline (1396.999 us; speedup 1.0000x reference)
//
#include <hip/hip_runtime.h>
#include <math.h>

// Problem sizes (fixed by reference)
// B=16, Ch=256 -> C=512, H=W=32, N=1024
// ws layout (float offsets):
//   g_x   : 0          .. 8388608    [16,512,1024]
//   sim   : 8388608    .. 12582912   [16,512,512]  (softmaxed in place -> attn)
//   wattn : 12582912   .. 14680064   [16,256,512]
//   rm    : 14680064   .. 14942208   [512,512]

static constexpr size_t OFF_GX    = 0;
static constexpr size_t OFF_SIM   = 8388608;
static constexpr size_t OFF_WATTN = 12582912;
static constexpr size_t OFF_RM    = 14680064;

// ---------------------------------------------------------------- rm = w1 @ w2^T
__global__ __launch_bounds__(256) void rm_kernel(const float* __restrict__ w1,
                                                 const float* __restrict__ w2,
                                                 float* __restrict__ rm) {
    int idx = blockIdx.x * 256 + threadIdx.x;   // 512*512 total
    int c = idx >> 9, d = idx & 511;
    float s = 0.f;
#pragma unroll
    for (int k = 0; k < 16; ++k) s = fmaf(w1[c * 16 + k], w2[d * 16 + k], s);
    rm[idx] = s;
}

// ---------------------------------------------------------------- 3x3 SAME conv
// grid (64, 16): blockIdx.x -> group of 8 output channels, blockIdx.y -> batch
// block 256: thread t -> spatial row y=t>>3, cols x4=(t&7)*4 .. +3
__global__ __launch_bounds__(256) void conv3x3_kernel(const float* __restrict__ x1,
                                                      const float* __restrict__ x2,
                                                      const float* __restrict__ gw,
                                                      float* __restrict__ gx) {
    __shared__ float xs[34 * 36];   // zero-padded plane, row stride 36 (16B-aligned rows)
    __shared__ float wlds[8 * 12];  // 8 co x 9 weights, padded to 12 for float4 reads

    const int t = threadIdx.x;
    const int b = blockIdx.y;
    const int co_base = blockIdx.x * 8;
    const int y  = t >> 3;         // 0..31
    const int x4 = (t & 7) * 4;    // 0,4,...,28

    for (int i = t; i < 34 * 36; i += 256) xs[i] = 0.f;

    float acc[8][4];
#pragma unroll
    for (int co = 0; co < 8; ++co)
#pragma unroll
        for (int j = 0; j < 4; ++j) acc[co][j] = 0.f;

    __syncthreads();  // zeroing must complete before interior staging overwrites

    for (int ci = 0; ci < 512; ++ci) {
        // stage interior 32x32 plane (borders stay zero)
        const float* src = (ci < 256) ? (x1 + ((size_t)(b * 256 + ci)) * 1024)
                                      : (x2 + ((size_t)(b * 256 + ci - 256)) * 1024);
        float4 v = ((const float4*)src)[t];        // elems t*4..t*4+3 => row y, cols x4..x4+3
        float* dst = &xs[(y + 1) * 36 + (x4 + 1)];
        dst[0] = v.x; dst[1] = v.y; dst[2] = v.z; dst[3] = v.w;

        if (t < 96) {
            int co = t / 12, i = t % 12;
            wlds[t] = (i < 9) ? gw[((size_t)(co_base + co) * 512 + ci) * 9 + i] : 0.f;
        }
        __syncthreads();

        // load the 3 input rows this thread needs: cols x4..x4+5 (two aligned float4s)
        float r[3][8];
#pragma unroll
        for (int dy = 0; dy < 3; ++dy) {
            float4 a = *(const float4*)&xs[(y + dy) * 36 + x4];
            float4 c = *(const float4*)&xs[(y + dy) * 36 + x4 + 4];
            r[dy][0] = a.x; r[dy][1] = a.y; r[dy][2] = a.z; r[dy][3] = a.w;
            r[dy][4] = c.x; r[dy][5] = c.y; r[dy][6] = c.z; r[dy][7] = c.w;
        }

#pragma unroll
        for (int co = 0; co < 8; ++co) {
            float4 wA = *(const float4*)&wlds[co * 12];
            float4 wB = *(const float4*)&wlds[co * 12 + 4];
            float wreg[9];
            wreg[0] = wA.x; wreg[1] = wA.y; wreg[2] = wA.z; wreg[3] = wA.w;
            wreg[4] = wB.x; wreg[5] = wB.y; wreg[6] = wB.z; wreg[7] = wB.w;
            wreg[8] = wlds[co * 12 + 8];
#pragma unroll
            for (int dy = 0; dy < 3; ++dy)
#pragma unroll
                for (int dx = 0; dx < 3; ++dx) {
                    float wv = wreg[dy * 3 + dx];
#pragma unroll
                    for (int j = 0; j < 4; ++j)
                        acc[co][j] = fmaf(r[dy][dx + j], wv, acc[co][j]);
                }
        }
        __syncthreads();
    }

    // epilogue: spatial index y*32+x4 == t*4
#pragma unroll
    for (int co = 0; co < 8; ++co) {
        float4 o = make_float4(acc[co][0], acc[co][1], acc[co][2], acc[co][3]);
        float* dst = gx + ((size_t)(b * 512 + co_base + co)) * 1024;
        ((float4*)dst)[t] = o;
    }
}

// ---------------------------------------------------------------- sim = (Q Q^T) * c^-0.5
// grid (8, 8, 16): x -> d-tile, y -> c-tile, z -> batch. 64x64 tile, 4x4 per thread.
__global__ __launch_bounds__(256) void sim_kernel(const float* __restrict__ x1,
                                                  const float* __restrict__ x2,
                                                  float* __restrict__ sim) {
    const int b = blockIdx.z;
    const int m0 = blockIdx.y * 64;
    const int n0 = blockIdx.x * 64;
    const float* A  = (m0 < 256) ? (x1 + ((size_t)b * 256 + m0) * 1024)
                                 : (x2 + ((size_t)b * 256 + (m0 - 256)) * 1024);
    const float* Bp = (n0 < 256) ? (x1 + ((size_t)b * 256 + n0) * 1024)
                                 : (x2 + ((size_t)b * 256 + (n0 - 256)) * 1024);

    __shared__ float As[16 * 68];
    __shared__ float Bs[16 * 68];

    const int t = threadIdx.x;
    const int tn = t & 15, tm = t >> 4;
    const int srow = t >> 2, sc4 = (t & 3) * 4;

    float acc[4][4];
#pragma unroll
    for (int i = 0; i < 4; ++i)
#pragma unroll
        for (int j = 0; j < 4; ++j) acc[i][j] = 0.f;

    for (int k0 = 0; k0 < 1024; k0 += 16) {
        float4 av = *(const float4*)&A [(size_t)srow * 1024 + k0 + sc4];
        float4 bv = *(const float4*)&Bp[(size_t)srow * 1024 + k0 + sc4];
        As[(sc4 + 0) * 68 + srow] = av.x;
        As[(sc4 + 1) * 68 + srow] = av.y;
        As[(sc4 + 2) * 68 + srow] = av.z;
        As[(sc4 + 3) * 68 + srow] = av.w;
        Bs[(sc4 + 0) * 68 + srow] = bv.x;
        Bs[(sc4 + 1) * 68 + srow] = bv.y;
        Bs[(sc4 + 2) * 68 + srow] = bv.z;
        Bs[(sc4 + 3) * 68 + srow] = bv.w;
        __syncthreads();
#pragma unroll
        for (int k = 0; k < 16; ++k) {
            float4 a4 = *(const float4*)&As[k * 68 + tm * 4];
            float4 b4 = *(const float4*)&Bs[k * 68 + tn * 4];
            float a[4] = {a4.x, a4.y, a4.z, a4.w};
            float bb[4] = {b4.x, b4.y, b4.z, b4.w};
#pragma unroll
            for (int i = 0; i < 4; ++i)
#pragma unroll
                for (int j = 0; j < 4; ++j) acc[i][j] = fmaf(a[i], bb[j], acc[i][j]);
        }
        __syncthreads();
    }

    const float scale = 0.04419417382415922f;  // 512^-0.5
    float* Cp = sim + ((size_t)b * 512 + m0) * 512 + n0;
#pragma unroll
    for (int i = 0; i < 4; ++i) {
        float4 o = make_float4(acc[i][0] * scale, acc[i][1] * scale,
                               acc[i][2] * scale, acc[i][3] * scale);
        *(float4*)&Cp[(size_t)(tm * 4 + i) * 512 + tn * 4] = o;
    }
}

// ---------------------------------------------------------------- softmax(sim + rm) in place
// one wave per row of 512; grid 2048, block 256 (4 waves)
__global__ __launch_bounds__(256) void softmax_kernel(float* __restrict__ sim,
                                                      const float* __restrict__ rm) {
    const int wave = threadIdx.x >> 6, lane = threadIdx.x & 63;
    const int row = blockIdx.x * 4 + wave;   // 0..8191 = b*512 + c
    const int c = row & 511;
    float* p = sim + (size_t)row * 512;
    const float* rp = rm + (size_t)c * 512;

    float v[8];
#pragma unroll
    for (int j = 0; j < 8; ++j) v[j] = p[j * 64 + lane] + rp[j * 64 + lane];

    float mx = v[0];
#pragma unroll
    for (int j = 1; j < 8; ++j) mx = fmaxf(mx, v[j]);
    for (int off = 32; off > 0; off >>= 1) mx = fmaxf(mx, __shfl_xor(mx, off, 64));

    float sum = 0.f;
#pragma unroll
    for (int j = 0; j < 8; ++j) { v[j] = __expf(v[j] - mx); sum += v[j]; }
    for (int off = 32; off > 0; off >>= 1) sum += __shfl_xor(sum, off, 64);

    float inv = 1.f / sum;
#pragma unroll
    for (int j = 0; j < 8; ++j) p[j * 64 + lane] = v[j] * inv;
}

// ---------------------------------------------------------------- C = A @ B (batched, row-major)
// grid (N/64, M/64, 16). A: M x K (batch stride sA; 0 = shared), B: K x N, C: M x N
__global__ __launch_bounds__(256) void gemm_nn_kernel(const float* __restrict__ A, size_t sA,
                                                      const float* __restrict__ Bm, size_t sB,
                                                      float* __restrict__ Cm, size_t sC,
                                                      int Mdim, int Ndim, int Kdim) {
    const int b = blockIdx.z;
    const float* Ab = A + (size_t)b * sA;
    const float* Bb = Bm + (size_t)b * sB;
    float* Cb = Cm + (size_t)b * sC;
    const int m0 = blockIdx.y * 64, n0 = blockIdx.x * 64;

    __shared__ float As[16 * 68];
    __shared__ float Bs[16 * 68];

    const int t = threadIdx.x;
    const int tn = t & 15, tm = t >> 4;
    const int arow = t >> 2, ac4 = (t & 3) * 4;   // A stage: 64 rows x 16 k
    const int brow = t >> 4, bc4 = (t & 15) * 4;  // B stage: 16 k x 64 n

    float acc[4][4];
#pragma unroll
    for (int i = 0; i < 4; ++i)
#pragma unroll
        for (int j = 0; j < 4; ++j) acc[i][j] = 0.f;

    for (int k0 = 0; k0 < Kdim; k0 += 16) {
        float4 av = *(const float4*)&Ab[(size_t)(m0 + arow) * Kdim + k0 + ac4];
        As[(ac4 + 0) * 68 + arow] = av.x;
        As[(ac4 + 1) * 68 + arow] = av.y;
        As[(ac4 + 2) * 68 + arow] = av.z;
        As[(ac4 + 3) * 68 + arow] = av.w;
        float4 bv = *(const float4*)&Bb[(size_t)(k0 + brow) * Ndim + n0 + bc4];
        *(float4*)&Bs[brow * 68 + bc4] = bv;
        __syncthreads();
#pragma unroll
        for (int k = 0; k < 16; ++k) {
            float4 a4 = *(const float4*)&As[k * 68 + tm * 4];
            float4 b4 = *(const float4*)&Bs[k * 68 + tn * 4];
            float a[4] = {a4.x, a4.y, a4.z, a4.w};
            float bb[4] = {b4.x, b4.y, b4.z, b4.w};
#pragma unroll
            for (int i = 0; i < 4; ++i)
#pragma unroll
                for (int j = 0; j < 4; ++j) acc[i][j] = fmaf(a[i], bb[j], acc[i][j]);
        }
        __syncthreads();
    }

#pragma unroll
    for (int i = 0; i < 4; ++i) {
        float4 o = make_float4(acc[i][0], acc[i][1], acc[i][2], acc[i][3]);
        *(float4*)&Cb[(size_t)(m0 + tm * 4 + i) * Ndim + n0 + tn * 4] = o;
    }
}

// ----------------------------------------------------------------
extern "C" void kernel_launch(void* const* d_in, const int* in_sizes, int n_in,
                              void* d_out, int out_size, void* d_ws, size_t ws_size,
                              hipStream_t stream) {
    (void)in_sizes; (void)n_in; (void)out_size; (void)ws_size;
    const float* x1 = (const float*)d_in[0];
    const float* x2 = (const float*)d_in[1];
    const float* gw = (const float*)d_in[2];
    const float* ww = (const float*)d_in[3];
    const float* w1 = (const float*)d_in[4];
    const float* w2 = (const float*)d_in[5];
    float* out = (float*)d_out;
    float* ws = (float*)d_ws;

    float* gx    = ws + OFF_GX;     // [16,512,1024] conv output (value)
    float* sim   = ws + OFF_SIM;    // [16,512,512]  sim -> attn (in place)
    float* wattn = ws + OFF_WATTN;  // [16,256,512]
    float* rm    = ws + OFF_RM;     // [512,512]

    rm_kernel<<<1024, 256, 0, stream>>>(w1, w2, rm);
    conv3x3_kernel<<<dim3(64, 16), 256, 0, stream>>>(x1, x2, gw, gx);
    sim_kernel<<<dim3(8, 8, 16), 256, 0, stream>>>(x1, x2, sim);
    softmax_kernel<<<2048, 256, 0, stream>>>(sim, rm);
    // wattn[b] = w_w (256x512) @ attn[b] (512x512)
    gemm_nn_kernel<<<dim3(8, 4, 16), 256, 0, stream>>>(
        ww, 0, sim, (size_t)512 * 512, wattn, (size_t)256 * 512, 256, 512, 512);
    // out[b] = wattn[b] (256x512) @ value[b] (512x1024)
    gemm_nn_kernel<<<dim3(16, 4, 16), 256, 0, stream>>>(
        wattn, (size_t)256 * 512, gx, (size_t)512 * 1024, out, (size_t)256 * 1024, 256, 1024, 512);
}

// Round 2
// 456.020 us; speedup vs baseline: 3.0635x; 3.0635x over previous
//
#include <hip/hip_runtime.h>
#include <math.h>

typedef float f32x4 __attribute__((ext_vector_type(4)));
typedef short s16x8 __attribute__((ext_vector_type(8)));
typedef unsigned int u32;
typedef unsigned short u16;

// ws layout (float offsets). xT/wA alias sim/wattn regions (dead until conv done).
static constexpr size_t OFF_GX    = 0;          // [16,512,1024] f32
static constexpr size_t OFF_SIM   = 8388608;    // [16,512,512]  f32 (attn in place)
static constexpr size_t OFF_WATTN = 12582912;   // [16,256,512]  f32
static constexpr size_t OFF_RM    = 14680064;   // [512,512]     f32
static constexpr size_t OFF_XT_F  = 8388608;    // xT bf16 [16,1156,512] (9,469,952 u16)
static constexpr size_t OFF_WA_F  = 13123584;   // wA bf16 [512,4608]    (2,359,296 u16)

__device__ __forceinline__ u16 f2bf(float f) {
    u32 u = __float_as_uint(f);
    u32 r = (u + 0x7FFFu + ((u >> 16) & 1u)) >> 16;   // RNE
    return (u16)r;
}

__device__ __forceinline__ void gload_lds16(const void* g, void* l) {
    __builtin_amdgcn_global_load_lds(
        (const u32 __attribute__((address_space(1)))*)(uintptr_t)g,
        (u32 __attribute__((address_space(3)))*)(uintptr_t)l, 16, 0, 0);
}

// ---------------------------------------------------------------- rm = w1 @ w2^T
__global__ __launch_bounds__(256) void rm_kernel(const float* __restrict__ w1,
                                                 const float* __restrict__ w2,
                                                 float* __restrict__ rm) {
    int idx = blockIdx.x * 256 + threadIdx.x;
    int c = idx >> 9, d = idx & 511;
    float s = 0.f;
#pragma unroll
    for (int k = 0; k < 16; ++k) s = fmaf(w1[c * 16 + k], w2[d * 16 + k], s);
    rm[idx] = s;
}

// ---------------------------------------------------------------- wA[co][r*512+ci] = bf16(g_w[co][ci][r])
__global__ __launch_bounds__(256) void wcast_kernel(const float* __restrict__ gw,
                                                    u16* __restrict__ wA) {
    int co = blockIdx.y;
    int k = blockIdx.x * 256 + threadIdx.x;   // 0..4607, k = r*512 + ci
    int r = k >> 9, ci = k & 511;
    wA[(size_t)co * 4608 + k] = f2bf(gw[(size_t)co * 4608 + ci * 9 + r]);
}

// ---------------------------------------------------------------- xT[b][p][ci] = bf16 padded channels-last
// p = yy*34+xx over 34x34 zero-padded plane; interior source = x[ci][(yy-1)*32 + xx-1]
__global__ __launch_bounds__(256) void xpose_kernel(const float* __restrict__ x1,
                                                    const float* __restrict__ x2,
                                                    u16* __restrict__ xT) {
    __shared__ u16 tile[64 * 72];   // [p_local][ci_local], pad 72 keeps 16B align
    const int b = blockIdx.z, ci0 = blockIdx.y * 64, p0 = blockIdx.x * 64;
    const float* src = (ci0 < 256) ? (x1 + ((size_t)(b * 256 + ci0)) * 1024)
                                   : (x2 + ((size_t)(b * 256 + ci0 - 256)) * 1024);
    const int t = threadIdx.x;
    {
        int ci_i = t >> 2, pj0 = (t & 3) * 16;
#pragma unroll
        for (int s = 0; s < 16; ++s) {
            int p = p0 + pj0 + s;
            float v = 0.f;
            if (p < 1156) {
                int yy = p / 34, xx = p - yy * 34;
                if (yy >= 1 && yy <= 32 && xx >= 1 && xx <= 32)
                    v = src[ci_i * 1024 + (yy - 1) * 32 + (xx - 1)];
            }
            tile[(pj0 + s) * 72 + ci_i] = f2bf(v);
        }
    }
    __syncthreads();
    {
        int p_i = t >> 2, c0 = (t & 3) * 16;
        int p = p0 + p_i;
        if (p < 1156) {
            u16* dst = xT + ((size_t)b * 1156 + p) * 512 + ci0 + c0;
            s16x8 v0 = *(const s16x8*)&tile[p_i * 72 + c0];
            s16x8 v1 = *(const s16x8*)&tile[p_i * 72 + c0 + 8];
            *(s16x8*)&dst[0] = v0;
            *(s16x8*)&dst[8] = v1;
        }
    }
}

// ---------------------------------------------------------------- conv as bf16 MFMA implicit GEMM
// C[b][co][n] = sum_k wA[co][k] * Bt[b][n][k],  Bt[n][r*512+ci] = xT[(y+r/3)*34 + x + r%3][ci]
// 128x128 tile, BK=64, 256 thr (4 waves, 2x2 of 64x64), XOR-swizzled LDS, global_load_lds x16B
__global__ __launch_bounds__(256) void conv_gemm(const u16* __restrict__ wA,
                                                 const u16* __restrict__ xT,
                                                 float* __restrict__ gx) {
    __shared__ __attribute__((aligned(16))) u16 As[128 * 64];
    __shared__ __attribute__((aligned(16))) u16 Bs[128 * 64];
    const int b = blockIdx.z, m0 = blockIdx.y * 128, n0 = blockIdx.x * 128;
    const int t = threadIdx.x, w = t >> 6, l = t & 63;
    const u16* xTb = xT + (size_t)b * 1156 * 512;

    // staging assignment: instr i of wave w covers tile rows rr = w*8 + i*32 + (l>>3)
    int gi[4], pb[4];
    const u16* agp[4];
    u16 *ald[4], *bld[4];
#pragma unroll
    for (int i = 0; i < 4; ++i) {
        int rr = w * 8 + i * 32 + (l >> 3);
        gi[i] = (l & 7) ^ (rr & 7);                      // swizzled k-group this lane fetches
        agp[i] = wA + (size_t)(m0 + rr) * 4608 + gi[i] * 8;
        int n = n0 + rr;
        pb[i] = (n >> 5) * 34 + (n & 31);
        ald[i] = &As[(w * 8 + i * 32) * 64];             // wave-uniform LDS base
        bld[i] = &Bs[(w * 8 + i * 32) * 64];
    }

    f32x4 acc[4][4] = {};
    const int wm = (w >> 1) * 64, wn = (w & 1) * 64;

    for (int kt = 0; kt < 72; ++kt) {
        int r = kt >> 3, ci0k = (kt & 7) << 6;
        int rdiv3 = (r * 11) >> 5;                        // r/3 for r in 0..8
        int poff = rdiv3 * 34 + (r - rdiv3 * 3);
        int aofs = r * 512 + ci0k;
        if (kt) __syncthreads();
#pragma unroll
        for (int i = 0; i < 4; ++i) gload_lds16(agp[i] + aofs, ald[i]);
#pragma unroll
        for (int i = 0; i < 4; ++i)
            gload_lds16(xTb + (size_t)(pb[i] + poff) * 512 + ci0k + gi[i] * 8, bld[i]);
        __syncthreads();

#pragma unroll
        for (int kk = 0; kk < 2; ++kk) {
            int gbase = kk * 4 + (l >> 4);                // k-group index 0..7
            s16x8 af[4], bf[4];
#pragma unroll
            for (int i = 0; i < 4; ++i) {
                int row = wm + i * 16 + (l & 15);
                af[i] = *(const s16x8*)&As[row * 64 + ((gbase ^ (row & 7)) << 3)];
            }
#pragma unroll
            for (int j = 0; j < 4; ++j) {
                int row = wn + j * 16 + (l & 15);
                bf[j] = *(const s16x8*)&Bs[row * 64 + ((gbase ^ (row & 7)) << 3)];
            }
#pragma unroll
            for (int i = 0; i < 4; ++i)
#pragma unroll
                for (int j = 0; j < 4; ++j)
                    acc[i][j] = __builtin_amdgcn_mfma_f32_16x16x32_bf16(af[i], bf[j], acc[i][j], 0, 0, 0);
        }
    }

    // epilogue: C/D layout col = lane&15, row = (lane>>4)*4 + reg
    const int col = l & 15, r4 = (l >> 4) * 4;
#pragma unroll
    for (int i = 0; i < 4; ++i)
#pragma unroll
        for (int j = 0; j < 4; ++j) {
#pragma unroll
            for (int reg = 0; reg < 4; ++reg) {
                int co = m0 + wm + i * 16 + r4 + reg;
                int n = n0 + wn + j * 16 + col;
                gx[((size_t)b * 512 + co) * 1024 + n] = acc[i][j][reg];
            }
        }
}

// ---------------------------------------------------------------- sim = (Q Q^T) * c^-0.5  (fp32)
__global__ __launch_bounds__(256) void sim_kernel(const float* __restrict__ x1,
                                                  const float* __restrict__ x2,
                                                  float* __restrict__ sim) {
    const int b = blockIdx.z;
    const int m0 = blockIdx.y * 64;
    const int n0 = blockIdx.x * 64;
    const float* A  = (m0 < 256) ? (x1 + ((size_t)b * 256 + m0) * 1024)
                                 : (x2 + ((size_t)b * 256 + (m0 - 256)) * 1024);
    const float* Bp = (n0 < 256) ? (x1 + ((size_t)b * 256 + n0) * 1024)
                                 : (x2 + ((size_t)b * 256 + (n0 - 256)) * 1024);

    __shared__ float Asm[16 * 68];
    __shared__ float Bsm[16 * 68];

    const int t = threadIdx.x;
    const int tn = t & 15, tm = t >> 4;
    const int srow = t >> 2, sc4 = (t & 3) * 4;

    float acc[4][4];
#pragma unroll
    for (int i = 0; i < 4; ++i)
#pragma unroll
        for (int j = 0; j < 4; ++j) acc[i][j] = 0.f;

    for (int k0 = 0; k0 < 1024; k0 += 16) {
        float4 av = *(const float4*)&A [(size_t)srow * 1024 + k0 + sc4];
        float4 bv = *(const float4*)&Bp[(size_t)srow * 1024 + k0 + sc4];
        Asm[(sc4 + 0) * 68 + srow] = av.x;
        Asm[(sc4 + 1) * 68 + srow] = av.y;
        Asm[(sc4 + 2) * 68 + srow] = av.z;
        Asm[(sc4 + 3) * 68 + srow] = av.w;
        Bsm[(sc4 + 0) * 68 + srow] = bv.x;
        Bsm[(sc4 + 1) * 68 + srow] = bv.y;
        Bsm[(sc4 + 2) * 68 + srow] = bv.z;
        Bsm[(sc4 + 3) * 68 + srow] = bv.w;
        __syncthreads();
#pragma unroll
        for (int k = 0; k < 16; ++k) {
            float4 a4 = *(const float4*)&Asm[k * 68 + tm * 4];
            float4 b4 = *(const float4*)&Bsm[k * 68 + tn * 4];
            float a[4] = {a4.x, a4.y, a4.z, a4.w};
            float bb[4] = {b4.x, b4.y, b4.z, b4.w};
#pragma unroll
            for (int i = 0; i < 4; ++i)
#pragma unroll
                for (int j = 0; j < 4; ++j) acc[i][j] = fmaf(a[i], bb[j], acc[i][j]);
        }
        __syncthreads();
    }

    const float scale = 0.04419417382415922f;  // 512^-0.5
    float* Cp = sim + ((size_t)b * 512 + m0) * 512 + n0;
#pragma unroll
    for (int i = 0; i < 4; ++i) {
        float4 o = make_float4(acc[i][0] * scale, acc[i][1] * scale,
                               acc[i][2] * scale, acc[i][3] * scale);
        *(float4*)&Cp[(size_t)(tm * 4 + i) * 512 + tn * 4] = o;
    }
}

// ---------------------------------------------------------------- softmax(sim + rm) in place
__global__ __launch_bounds__(256) void softmax_kernel(float* __restrict__ sim,
                                                      const float* __restrict__ rm) {
    const int wave = threadIdx.x >> 6, lane = threadIdx.x & 63;
    const int row = blockIdx.x * 4 + wave;
    const int c = row & 511;
    float* p = sim + (size_t)row * 512;
    const float* rp = rm + (size_t)c * 512;

    float v[8];
#pragma unroll
    for (int j = 0; j < 8; ++j) v[j] = p[j * 64 + lane] + rp[j * 64 + lane];

    float mx = v[0];
#pragma unroll
    for (int j = 1; j < 8; ++j) mx = fmaxf(mx, v[j]);
    for (int off = 32; off > 0; off >>= 1) mx = fmaxf(mx, __shfl_xor(mx, off, 64));

    float sum = 0.f;
#pragma unroll
    for (int j = 0; j < 8; ++j) { v[j] = __expf(v[j] - mx); sum += v[j]; }
    for (int off = 32; off > 0; off >>= 1) sum += __shfl_xor(sum, off, 64);

    float inv = 1.f / sum;
#pragma unroll
    for (int j = 0; j < 8; ++j) p[j * 64 + lane] = v[j] * inv;
}

// ---------------------------------------------------------------- C = A @ B (batched, row-major, fp32)
__global__ __launch_bounds__(256) void gemm_nn_kernel(const float* __restrict__ A, size_t sA,
                                                      const float* __restrict__ Bm, size_t sB,
                                                      float* __restrict__ Cm, size_t sC,
                                                      int Mdim, int Ndim, int Kdim) {
    const int b = blockIdx.z;
    const float* Ab = A + (size_t)b * sA;
    const float* Bb = Bm + (size_t)b * sB;
    float* Cb = Cm + (size_t)b * sC;
    const int m0 = blockIdx.y * 64, n0 = blockIdx.x * 64;

    __shared__ float Asm[16 * 68];
    __shared__ float Bsm[16 * 68];

    const int t = threadIdx.x;
    const int tn = t & 15, tm = t >> 4;
    const int arow = t >> 2, ac4 = (t & 3) * 4;
    const int brow = t >> 4, bc4 = (t & 15) * 4;

    float acc[4][4];
#pragma unroll
    for (int i = 0; i < 4; ++i)
#pragma unroll
        for (int j = 0; j < 4; ++j) acc[i][j] = 0.f;

    for (int k0 = 0; k0 < Kdim; k0 += 16) {
        float4 av = *(const float4*)&Ab[(size_t)(m0 + arow) * Kdim + k0 + ac4];
        Asm[(ac4 + 0) * 68 + arow] = av.x;
        Asm[(ac4 + 1) * 68 + arow] = av.y;
        Asm[(ac4 + 2) * 68 + arow] = av.z;
        Asm[(ac4 + 3) * 68 + arow] = av.w;
        float4 bv = *(const float4*)&Bb[(size_t)(k0 + brow) * Ndim + n0 + bc4];
        *(float4*)&Bsm[brow * 68 + bc4] = bv;
        __syncthreads();
#pragma unroll
        for (int k = 0; k < 16; ++k) {
            float4 a4 = *(const float4*)&Asm[k * 68 + tm * 4];
            float4 b4 = *(const float4*)&Bsm[k * 68 + tn * 4];
            float a[4] = {a4.x, a4.y, a4.z, a4.w};
            float bb[4] = {b4.x, b4.y, b4.z, b4.w};
#pragma unroll
            for (int i = 0; i < 4; ++i)
#pragma unroll
                for (int j = 0; j < 4; ++j) acc[i][j] = fmaf(a[i], bb[j], acc[i][j]);
        }
        __syncthreads();
    }

#pragma unroll
    for (int i = 0; i < 4; ++i) {
        float4 o = make_float4(acc[i][0], acc[i][1], acc[i][2], acc[i][3]);
        *(float4*)&Cb[(size_t)(m0 + tm * 4 + i) * Ndim + n0 + tn * 4] = o;
    }
}

// ----------------------------------------------------------------
extern "C" void kernel_launch(void* const* d_in, const int* in_sizes, int n_in,
                              void* d_out, int out_size, void* d_ws, size_t ws_size,
                              hipStream_t stream) {
    (void)in_sizes; (void)n_in; (void)out_size; (void)ws_size;
    const float* x1 = (const float*)d_in[0];
    const float* x2 = (const float*)d_in[1];
    const float* gw = (const float*)d_in[2];
    const float* ww = (const float*)d_in[3];
    const float* w1 = (const float*)d_in[4];
    const float* w2 = (const float*)d_in[5];
    float* out = (float*)d_out;
    float* ws = (float*)d_ws;

    float* gx    = ws + OFF_GX;
    float* sim   = ws + OFF_SIM;
    float* wattn = ws + OFF_WATTN;
    float* rm    = ws + OFF_RM;
    u16*   xT    = (u16*)(ws + OFF_XT_F);
    u16*   wA    = (u16*)(ws + OFF_WA_F);

    rm_kernel<<<1024, 256, 0, stream>>>(w1, w2, rm);
    wcast_kernel<<<dim3(18, 512), 256, 0, stream>>>(gw, wA);
    xpose_kernel<<<dim3(19, 8, 16), 256, 0, stream>>>(x1, x2, xT);
    conv_gemm<<<dim3(8, 4, 16), 256, 0, stream>>>(wA, xT, gx);
    sim_kernel<<<dim3(8, 8, 16), 256, 0, stream>>>(x1, x2, sim);
    softmax_kernel<<<2048, 256, 0, stream>>>(sim, rm);
    gemm_nn_kernel<<<dim3(8, 4, 16), 256, 0, stream>>>(
        ww, 0, sim, (size_t)512 * 512, wattn, (size_t)256 * 512, 256, 512, 512);
    gemm_nn_kernel<<<dim3(16, 4, 16), 256, 0, stream>>>(
        wattn, (size_t)256 * 512, gx, (size_t)512 * 1024, out, (size_t)256 * 1024, 256, 1024, 512);
}

// Round 3
// 312.983 us; speedup vs baseline: 4.4635x; 1.4570x over previous
//
#include <hip/hip_runtime.h>
#include <math.h>

typedef float f32x4 __attribute__((ext_vector_type(4)));
typedef short s16x8 __attribute__((ext_vector_type(8)));
typedef unsigned int u32;
typedef unsigned short u16;
typedef u16 u16x4 __attribute__((ext_vector_type(4)));

// ---------------- ws layout (float offsets), lifetime-aliased ----------------
// B region: sim f32 [16,512,512] (k3..k5)  -> vT bf16 [16,1024,512] (k10..k11)
// C region: xq bf16 [16,512,1024] (k2..k3) -> xT bf16 [16,1156,512] (k8..k10)
// A region: attnT bf16 [16,512,512] (k5..k7) + wattn bf16 [16,256,512] (k7..k11)
static constexpr size_t OFF_SIM   = 0;         // also vT
static constexpr size_t OFF_XQ    = 4194304;   // also xT (4,734,976 floats)
static constexpr size_t OFF_ATTNT = 8929280;
static constexpr size_t OFF_WATTN = 11026432;
static constexpr size_t OFF_WA    = 12075008;
static constexpr size_t OFF_RM    = 13254656;
static constexpr size_t OFF_WWB   = 13516800;  // end 13,582,336 floats = 54.3 MB

__device__ __forceinline__ u16 f2bf(float f) {
    u32 u = __float_as_uint(f);
    u32 r = (u + 0x7FFFu + ((u >> 16) & 1u)) >> 16;   // RNE
    return (u16)r;
}

__device__ __forceinline__ void gload_lds16(const void* g, void* l) {
    __builtin_amdgcn_global_load_lds(
        (const u32 __attribute__((address_space(1)))*)(uintptr_t)g,
        (u32 __attribute__((address_space(3)))*)(uintptr_t)l, 16, 0, 0);
}

// ---------------------------------------------------------------- rm = w1 @ w2^T
__global__ __launch_bounds__(256) void rm_kernel(const float* __restrict__ w1,
                                                 const float* __restrict__ w2,
                                                 float* __restrict__ rm) {
    int idx = blockIdx.x * 256 + threadIdx.x;
    int c = idx >> 9, d = idx & 511;
    float s = 0.f;
#pragma unroll
    for (int k = 0; k < 16; ++k) s = fmaf(w1[c * 16 + k], w2[d * 16 + k], s);
    rm[idx] = s;
}

// ---------------------------------------------------------------- xq = bf16(concat(x1,x2))  [b,512,1024]
__global__ __launch_bounds__(256) void xq_cast(const float* __restrict__ x1,
                                               const float* __restrict__ x2,
                                               u16* __restrict__ xq) {
    int row = blockIdx.x;                 // b*512 + c, 8192 rows
    int b = row >> 9, c = row & 511;
    const float* src = (c < 256) ? (x1 + ((size_t)(b * 256 + c)) * 1024)
                                 : (x2 + ((size_t)(b * 256 + c - 256)) * 1024);
    u16* dst = xq + (size_t)row * 1024;
    float4 v = ((const float4*)src)[threadIdx.x];
    u16x4 pk = {f2bf(v.x), f2bf(v.y), f2bf(v.z), f2bf(v.w)};
    *(u16x4*)&dst[threadIdx.x * 4] = pk;
}

// ---------------------------------------------------------------- wwb = bf16(w_w)  [256,512]
__global__ __launch_bounds__(256) void wwcast_kernel(const float* __restrict__ ww,
                                                     u16* __restrict__ wwb) {
    int idx = blockIdx.x * 256 + threadIdx.x;   // 32768 float4 groups
    float4 v = ((const float4*)ww)[idx];
    u16x4 pk = {f2bf(v.x), f2bf(v.y), f2bf(v.z), f2bf(v.w)};
    *(u16x4*)&wwb[(size_t)idx * 4] = pk;
}

// ---------------------------------------------------------------- wA[co][r*512+ci] = bf16(g_w[co][ci][r])
__global__ __launch_bounds__(256) void wcast_kernel(const float* __restrict__ gw,
                                                    u16* __restrict__ wA) {
    int co = blockIdx.y;
    int k = blockIdx.x * 256 + threadIdx.x;   // k = r*512 + ci
    int r = k >> 9, ci = k & 511;
    wA[(size_t)co * 4608 + k] = f2bf(gw[(size_t)co * 4608 + ci * 9 + r]);
}

// ---------------------------------------------------------------- xT[b][p][ci] bf16, 34x34 zero-padded
__global__ __launch_bounds__(256) void xpose_kernel(const float* __restrict__ x1,
                                                    const float* __restrict__ x2,
                                                    u16* __restrict__ xT) {
    __shared__ u16 tile[64 * 72];
    const int b = blockIdx.z, ci0 = blockIdx.y * 64, p0 = blockIdx.x * 64;
    const float* src = (ci0 < 256) ? (x1 + ((size_t)(b * 256 + ci0)) * 1024)
                                   : (x2 + ((size_t)(b * 256 + ci0 - 256)) * 1024);
    const int t = threadIdx.x;
    {
        int ci_i = t >> 2, pj0 = (t & 3) * 16;
#pragma unroll
        for (int s = 0; s < 16; ++s) {
            int p = p0 + pj0 + s;
            float v = 0.f;
            if (p < 1156) {
                int yy = p / 34, xx = p - yy * 34;
                if (yy >= 1 && yy <= 32 && xx >= 1 && xx <= 32)
                    v = src[ci_i * 1024 + (yy - 1) * 32 + (xx - 1)];
            }
            tile[(pj0 + s) * 72 + ci_i] = f2bf(v);
        }
    }
    __syncthreads();
    {
        int p_i = t >> 2, c0 = (t & 3) * 16;
        int p = p0 + p_i;
        if (p < 1156) {
            u16* dst = xT + ((size_t)b * 1156 + p) * 512 + ci0 + c0;
            *(s16x8*)&dst[0] = *(const s16x8*)&tile[p_i * 72 + c0];
            *(s16x8*)&dst[8] = *(const s16x8*)&tile[p_i * 72 + c0 + 8];
        }
    }
}

// ---------------------------------------------------------------- generic bf16 MFMA NT GEMM
// C[b][m][n] = sum_k A[b][m][k] * B[b][n][k].  128x128 tile, BK=64, 4 waves 2x2.
// MODE 0: f32 out, val = acc*scale + rm[m*ldc+n]   (sim)
// MODE 1: bf16 out                                  (wattn)
// MODE 2: f32 out                                   (final out)
template <int MODE>
__global__ __launch_bounds__(256) void gemm_nt(const u16* __restrict__ A, size_t sA,
                                               const u16* __restrict__ B, size_t sB,
                                               void* __restrict__ Cv, size_t sC,
                                               int K, int ldc,
                                               const float* __restrict__ rmp) {
    __shared__ __attribute__((aligned(16))) u16 As[128 * 64];
    __shared__ __attribute__((aligned(16))) u16 Bs[128 * 64];
    const int b = blockIdx.z, m0 = blockIdx.y * 128, n0 = blockIdx.x * 128;
    const int t = threadIdx.x, w = t >> 6, l = t & 63;
    const u16* Ab = A + (size_t)b * sA;
    const u16* Bb = B + (size_t)b * sB;

    const u16 *agp[4], *bgp[4];
    u16 *ald[4], *bld[4];
#pragma unroll
    for (int i = 0; i < 4; ++i) {
        int rr = w * 8 + i * 32 + (l >> 3);
        int gi = (l & 7) ^ (rr & 7);
        agp[i] = Ab + (size_t)(m0 + rr) * K + gi * 8;
        bgp[i] = Bb + (size_t)(n0 + rr) * K + gi * 8;
        ald[i] = &As[(w * 8 + i * 32) * 64];
        bld[i] = &Bs[(w * 8 + i * 32) * 64];
    }

    f32x4 acc[4][4] = {};
    const int wm = (w >> 1) * 64, wn = (w & 1) * 64;
    const int nkt = K >> 6;
    for (int kt = 0; kt < nkt; ++kt) {
        int ko = kt << 6;
        if (kt) __syncthreads();
#pragma unroll
        for (int i = 0; i < 4; ++i) gload_lds16(agp[i] + ko, ald[i]);
#pragma unroll
        for (int i = 0; i < 4; ++i) gload_lds16(bgp[i] + ko, bld[i]);
        __syncthreads();
#pragma unroll
        for (int kk = 0; kk < 2; ++kk) {
            int gbase = kk * 4 + (l >> 4);
            s16x8 af[4], bf[4];
#pragma unroll
            for (int i = 0; i < 4; ++i) {
                int row = wm + i * 16 + (l & 15);
                af[i] = *(const s16x8*)&As[row * 64 + ((gbase ^ (row & 7)) << 3)];
            }
#pragma unroll
            for (int j = 0; j < 4; ++j) {
                int row = wn + j * 16 + (l & 15);
                bf[j] = *(const s16x8*)&Bs[row * 64 + ((gbase ^ (row & 7)) << 3)];
            }
#pragma unroll
            for (int i = 0; i < 4; ++i)
#pragma unroll
                for (int j = 0; j < 4; ++j)
                    acc[i][j] = __builtin_amdgcn_mfma_f32_16x16x32_bf16(af[i], bf[j], acc[i][j], 0, 0, 0);
        }
    }

    const int col = l & 15, r4 = (l >> 4) * 4;
    const float scale = 0.04419417382415922f;  // 512^-0.5
#pragma unroll
    for (int i = 0; i < 4; ++i)
#pragma unroll
        for (int j = 0; j < 4; ++j)
#pragma unroll
            for (int reg = 0; reg < 4; ++reg) {
                int m = m0 + wm + i * 16 + r4 + reg;
                int n = n0 + wn + j * 16 + col;
                if (MODE == 0) {
                    float* C = (float*)Cv + (size_t)b * sC;
                    C[(size_t)m * ldc + n] = acc[i][j][reg] * scale + rmp[(size_t)m * ldc + n];
                } else if (MODE == 1) {
                    u16* C = (u16*)Cv + (size_t)b * sC;
                    C[(size_t)m * ldc + n] = f2bf(acc[i][j][reg]);
                } else {
                    float* C = (float*)Cv + (size_t)b * sC;
                    C[(size_t)m * ldc + n] = acc[i][j][reg];
                }
            }
}

// ---------------------------------------------------------------- softmax(sim) in place (rm pre-added)
__global__ __launch_bounds__(256) void softmax_kernel(float* __restrict__ sim) {
    const int wave = threadIdx.x >> 6, lane = threadIdx.x & 63;
    const int row = blockIdx.x * 4 + wave;
    float* p = sim + (size_t)row * 512;

    float v[8];
#pragma unroll
    for (int j = 0; j < 8; ++j) v[j] = p[j * 64 + lane];

    float mx = v[0];
#pragma unroll
    for (int j = 1; j < 8; ++j) mx = fmaxf(mx, v[j]);
    for (int off = 32; off > 0; off >>= 1) mx = fmaxf(mx, __shfl_xor(mx, off, 64));

    float sum = 0.f;
#pragma unroll
    for (int j = 0; j < 8; ++j) { v[j] = __expf(v[j] - mx); sum += v[j]; }
    for (int off = 32; off > 0; off >>= 1) sum += __shfl_xor(sum, off, 64);

    float inv = 1.f / sum;
#pragma unroll
    for (int j = 0; j < 8; ++j) p[j * 64 + lane] = v[j] * inv;
}

// ---------------------------------------------------------------- attnT[b][d][c] = bf16(attn[b][c][d])
__global__ __launch_bounds__(256) void tcast_attn(const float* __restrict__ attn,
                                                  u16* __restrict__ attnT) {
    __shared__ u16 tile[64 * 72];
    const int b = blockIdx.z, d0 = blockIdx.x * 64, c0 = blockIdx.y * 64;
    const int t = threadIdx.x;
    const float* src = attn + ((size_t)b * 512 + c0) * 512 + d0;
    {
        int c_l = t >> 4, d4 = (t & 15) * 4;
#pragma unroll
        for (int s = 0; s < 4; ++s) {
            float4 v = *(const float4*)&src[(size_t)(c_l + s * 16) * 512 + d4];
            tile[(d4 + 0) * 72 + c_l + s * 16] = f2bf(v.x);
            tile[(d4 + 1) * 72 + c_l + s * 16] = f2bf(v.y);
            tile[(d4 + 2) * 72 + c_l + s * 16] = f2bf(v.z);
            tile[(d4 + 3) * 72 + c_l + s * 16] = f2bf(v.w);
        }
    }
    __syncthreads();
    {
        int d_l = t >> 2;
        u16* dst = attnT + ((size_t)b * 512 + d0 + d_l) * 512 + c0;
#pragma unroll
        for (int rep = 0; rep < 2; ++rep) {
            int c8 = (t & 3) * 8 + rep * 32;
            *(s16x8*)&dst[c8] = *(const s16x8*)&tile[d_l * 72 + c8];
        }
    }
}

// ---------------------------------------------------------------- conv as bf16 MFMA implicit GEMM
// writes vT[b][n][co] bf16 via in-LDS XOR-swizzled transpose epilogue
__global__ __launch_bounds__(256) void conv_gemm(const u16* __restrict__ wA,
                                                 const u16* __restrict__ xT,
                                                 u16* __restrict__ vT) {
    __shared__ __attribute__((aligned(16))) u16 smem[128 * 128];
    u16* As = smem;               // 128 x 64
    u16* Bs = smem + 128 * 64;    // 128 x 64
    const int b = blockIdx.z, m0 = blockIdx.y * 128, n0 = blockIdx.x * 128;
    const int t = threadIdx.x, w = t >> 6, l = t & 63;
    const u16* xTb = xT + (size_t)b * 1156 * 512;

    int gi[4], pb[4];
    const u16* agp[4];
    u16 *ald[4], *bld[4];
#pragma unroll
    for (int i = 0; i < 4; ++i) {
        int rr = w * 8 + i * 32 + (l >> 3);
        gi[i] = (l & 7) ^ (rr & 7);
        agp[i] = wA + (size_t)(m0 + rr) * 4608 + gi[i] * 8;
        int n = n0 + rr;
        pb[i] = (n >> 5) * 34 + (n & 31);
        ald[i] = &As[(w * 8 + i * 32) * 64];
        bld[i] = &Bs[(w * 8 + i * 32) * 64];
    }

    f32x4 acc[4][4] = {};
    const int wm = (w >> 1) * 64, wn = (w & 1) * 64;

    for (int kt = 0; kt < 72; ++kt) {
        int r = kt >> 3, ci0k = (kt & 7) << 6;
        int rdiv3 = (r * 11) >> 5;
        int poff = rdiv3 * 34 + (r - rdiv3 * 3);
        int aofs = r * 512 + ci0k;
        if (kt) __syncthreads();
#pragma unroll
        for (int i = 0; i < 4; ++i) gload_lds16(agp[i] + aofs, ald[i]);
#pragma unroll
        for (int i = 0; i < 4; ++i)
            gload_lds16(xTb + (size_t)(pb[i] + poff) * 512 + ci0k + gi[i] * 8, bld[i]);
        __syncthreads();

#pragma unroll
        for (int kk = 0; kk < 2; ++kk) {
            int gbase = kk * 4 + (l >> 4);
            s16x8 af[4], bf[4];
#pragma unroll
            for (int i = 0; i < 4; ++i) {
                int row = wm + i * 16 + (l & 15);
                af[i] = *(const s16x8*)&As[row * 64 + ((gbase ^ (row & 7)) << 3)];
            }
#pragma unroll
            for (int j = 0; j < 4; ++j) {
                int row = wn + j * 16 + (l & 15);
                bf[j] = *(const s16x8*)&Bs[row * 64 + ((gbase ^ (row & 7)) << 3)];
            }
#pragma unroll
            for (int i = 0; i < 4; ++i)
#pragma unroll
                for (int j = 0; j < 4; ++j)
                    acc[i][j] = __builtin_amdgcn_mfma_f32_16x16x32_bf16(af[i], bf[j], acc[i][j], 0, 0, 0);
        }
    }

    // ---- epilogue: transpose C tile in LDS, write vT[n][co] bf16 coalesced ----
    __syncthreads();   // all LDS reads of K-loop done before overwrite
    const int col = l & 15, r4 = (l >> 4) * 4;
#pragma unroll
    for (int i = 0; i < 4; ++i)
#pragma unroll
        for (int j = 0; j < 4; ++j) {
            int n_l = wn + j * 16 + col;
            int co_b = wm + i * 16 + r4;
            u16x4 pk = {f2bf(acc[i][j][0]), f2bf(acc[i][j][1]),
                        f2bf(acc[i][j][2]), f2bf(acc[i][j][3])};
            *(u16x4*)&smem[n_l * 128 + (co_b ^ ((n_l & 15) << 3))] = pk;
        }
    __syncthreads();
    u16* vTb = vT + (size_t)b * 1024 * 512;
    {
        int n_l = t >> 1;
#pragma unroll
        for (int rep = 0; rep < 8; ++rep) {
            int c0 = (((t & 1) + rep * 2) << 3);   // 0..120 step 8
            s16x8 v = *(const s16x8*)&smem[n_l * 128 + (c0 ^ ((n_l & 15) << 3))];
            *(s16x8*)&vTb[(size_t)(n0 + n_l) * 512 + m0 + c0] = v;
        }
    }
}

// ----------------------------------------------------------------
extern "C" void kernel_launch(void* const* d_in, const int* in_sizes, int n_in,
                              void* d_out, int out_size, void* d_ws, size_t ws_size,
                              hipStream_t stream) {
    (void)in_sizes; (void)n_in; (void)out_size; (void)ws_size;
    const float* x1 = (const float*)d_in[0];
    const float* x2 = (const float*)d_in[1];
    const float* gw = (const float*)d_in[2];
    const float* ww = (const float*)d_in[3];
    const float* w1 = (const float*)d_in[4];
    const float* w2 = (const float*)d_in[5];
    float* out = (float*)d_out;
    float* ws = (float*)d_ws;

    float* sim   = ws + OFF_SIM;
    float* rm    = ws + OFF_RM;
    u16* xq    = (u16*)(ws + OFF_XQ);
    u16* xT    = (u16*)(ws + OFF_XQ);      // aliases xq (dead after sim gemm)
    u16* vT    = (u16*)(ws + OFF_SIM);     // aliases sim (dead after tcast)
    u16* attnT = (u16*)(ws + OFF_ATTNT);
    u16* wattn = (u16*)(ws + OFF_WATTN);
    u16* wA    = (u16*)(ws + OFF_WA);
    u16* wwb   = (u16*)(ws + OFF_WWB);

    rm_kernel<<<1024, 256, 0, stream>>>(w1, w2, rm);
    xq_cast<<<8192, 256, 0, stream>>>(x1, x2, xq);
    // sim = xq @ xq^T * scale + rm
    gemm_nt<0><<<dim3(4, 4, 16), 256, 0, stream>>>(
        xq, (size_t)512 * 1024, xq, (size_t)512 * 1024, sim, (size_t)512 * 512, 1024, 512, rm);
    softmax_kernel<<<2048, 256, 0, stream>>>(sim);
    tcast_attn<<<dim3(8, 8, 16), 256, 0, stream>>>(sim, attnT);
    wwcast_kernel<<<128, 256, 0, stream>>>(ww, wwb);
    // wattn[b][o][d] = sum_c wwb[o][c] * attnT[b][d][c]  (bf16 out)
    gemm_nt<1><<<dim3(4, 2, 16), 256, 0, stream>>>(
        wwb, 0, attnT, (size_t)512 * 512, wattn, (size_t)256 * 512, 512, 512, nullptr);
    xpose_kernel<<<dim3(19, 8, 16), 256, 0, stream>>>(x1, x2, xT);
    wcast_kernel<<<dim3(18, 512), 256, 0, stream>>>(gw, wA);
    conv_gemm<<<dim3(8, 4, 16), 256, 0, stream>>>(wA, xT, vT);
    // out[b][o][n] = sum_d wattn[b][o][d] * vT[b][n][d]  (f32 out)
    gemm_nt<2><<<dim3(8, 2, 16), 256, 0, stream>>>(
        wattn, (size_t)256 * 512, vT, (size_t)1024 * 512, out, (size_t)256 * 1024, 512, 1024, nullptr);
}